// Round 2
// baseline (530.444 us; speedup 1.0000x reference)
//
#include <hip/hip_runtime.h>

// LQR KKT solve via backward Riccati recursion + forward rollout.
// T=128, n_state=16, n_ctrl=8, n_all=24. Single block, 256 threads.
// mu_t computed as P_t x_t + p_t (stable), NOT via the costate recursion
// (A has spectral radius ~1.2 -> costate recursion amplifies error 1.2^128).

constexpr int T  = 128;
constexpr int NA = 24;

__global__ __launch_bounds__(256, 1)
void lqr_solve(const float* __restrict__ gA,
               const float* __restrict__ gB,
               const float* __restrict__ gx0,
               const float* __restrict__ gC,
               const float* __restrict__ gc,
               float* __restrict__ out,
               float* __restrict__ Pws,   // [T*256] scratch: P_t row-major
               float* __restrict__ pws)   // [T*16]  scratch: p_t
{
    __shared__ float A_sh[16][16];   // A row-major
    __shared__ float At_sh[16][16];  // A^T row-major (contiguous columns of A)
    __shared__ float B_sh[16][8];
    __shared__ float Bt_sh[8][16];
    __shared__ float P_sh[2][16][16]; // double-buffered P_{t+1} / P_t
    __shared__ float p_sh[2][16];
    __shared__ float Wt[16][16];     // Wt[j][k] = (P' A)[k][j]  (transposed)
    __shared__ float Vt[8][16];      // Vt[j][k] = (P' B)[k][j]
    __shared__ float Gu[16][8];      // S + A^T P' B
    __shared__ float Aug[2][8][27];  // ping-pong [H | G | rhs], 25 used cols
    __shared__ float Kall[T][8][16];
    __shared__ float kall[T][8];
    __shared__ float c_sh[T][NA];
    __shared__ float z_sh[T][NA];    // x_t = [0:16), u_t = [16:24)
    __shared__ float Csh[2][24][25]; // double-buffered C_t (padded rows)

    const int tid = threadIdx.x;

    // ---- init: load A, B, c, C_{T-1}; P_T = 0, p_T = 0 ----
    {
        const int i = tid >> 4, j = tid & 15;
        const float v = gA[tid];
        A_sh[i][j] = v; At_sh[j][i] = v;
        P_sh[0][i][j] = 0.0f;
    }
    if (tid < 128) {
        const int i = tid >> 3, j = tid & 7;
        const float v = gB[tid];
        B_sh[i][j] = v; Bt_sh[j][i] = v;
    }
    if (tid < 16) p_sh[0][tid] = 0.0f;
    for (int idx = tid; idx < T * NA; idx += 256) c_sh[idx / NA][idx % NA] = gc[idx];
    for (int idx = tid; idx < 576; idx += 256)
        Csh[0][idx / 24][idx % 24] = gC[(T - 1) * 576 + idx];
    __syncthreads();

    // ---- backward Riccati pass ----
    int pb = 0; // P_sh buffer holding P_{t+1}
    for (int t = T - 1; t >= 0; --t) {
        const int cb = (T - 1 - t) & 1; // Csh buffer holding C_t

        // register-prefetch C_{t-1} (written to LDS in phase 5)
        float pf0 = 0.f, pf1 = 0.f, pf2 = 0.f;
        if (t > 0) {
            const float* src = gC + (size_t)(t - 1) * 576;
            pf0 = src[tid];
            pf1 = src[tid + 256];
            if (tid < 64) pf2 = src[tid + 512];
        }

        // phase 1+2: Wt = (P'A)^T, Vt = (P'B)^T  (contiguous row reads)
        {
            const int j = tid >> 4, k = tid & 15;
            float s = 0.f;
            #pragma unroll
            for (int q = 0; q < 16; ++q) s = fmaf(P_sh[pb][k][q], At_sh[j][q], s);
            Wt[j][k] = s;
            if (tid < 128) {
                float s2 = 0.f;
                #pragma unroll
                for (int q = 0; q < 16; ++q) s2 = fmaf(P_sh[pb][k][q], Bt_sh[j][q], s2);
                Vt[j][k] = s2;
            }
        }
        __syncthreads();

        // phase 3: Aug = [H | G | rhs] (8x25) and Gu = S + A^T V (16x8)
        if (tid < 200) {
            const int i = tid / 25, j = tid % 25;
            float s;
            if (j < 8) {                    // H = R + B^T P' B
                s = Csh[cb][16 + i][16 + j];
                #pragma unroll
                for (int q = 0; q < 16; ++q) s = fmaf(Bt_sh[i][q], Vt[j][q], s);
            } else if (j < 24) {            // G = S^t + B^T P' A
                const int jj = j - 8;
                s = Csh[cb][16 + i][jj];
                #pragma unroll
                for (int q = 0; q < 16; ++q) s = fmaf(Bt_sh[i][q], Wt[jj][q], s);
            } else {                        // rhs = r + B^T p'
                s = c_sh[t][16 + i];
                #pragma unroll
                for (int q = 0; q < 16; ++q) s = fmaf(Bt_sh[i][q], p_sh[pb][q], s);
            }
            Aug[0][i][j] = s;
        }
        if (tid < 128) {
            const int i = tid >> 3, j = tid & 7;
            float s = Csh[cb][i][16 + j];
            #pragma unroll
            for (int q = 0; q < 16; ++q) s = fmaf(At_sh[i][q], Vt[j][q], s);
            Gu[i][j] = s;
        }
        __syncthreads();

        // phase 4: Gauss-Jordan on Aug (H is SPD, >= I: no pivoting needed).
        // ping-pong buffers -> 1 barrier per pivot; result lands in Aug[0].
        #pragma unroll
        for (int kk = 0; kk < 8; ++kk) {
            const int rb = kk & 1, wb = rb ^ 1;
            if (tid < 200) {
                const int i = tid / 25, j = tid % 25;
                const float piv = Aug[rb][kk][kk];
                const float inv = 1.0f / piv;
                float v;
                if (i == kk) v = Aug[rb][i][j] * inv;
                else v = Aug[rb][i][j] - Aug[rb][i][kk] * inv * Aug[rb][kk][j];
                Aug[wb][i][j] = v;
            }
            __syncthreads();
        }
        // Aug[0] = [I | K | k],  K = H^-1 G,  k = H^-1 rhs

        // phase 5: P_t = Q + A^T W - Gu K ; p_t = q + A^T p' - Gu k ; save K,k
        {
            const int i = tid >> 4, j = tid & 15;
            float s = Csh[cb][i][j];  // Q
            #pragma unroll
            for (int q = 0; q < 16; ++q) s = fmaf(At_sh[i][q], Wt[j][q], s);
            float s2 = 0.f;
            #pragma unroll
            for (int q = 0; q < 8; ++q) s2 = fmaf(Gu[i][q], Aug[0][q][8 + j], s2);
            const float v = s - s2;
            P_sh[pb ^ 1][i][j] = v;
            Pws[t * 256 + tid] = v;   // for mu_t = P_t x_t + p_t later
        }
        if (tid < 128) {
            const int i = tid >> 4, j = tid & 15;
            Kall[t][i][j] = Aug[0][i][8 + j];
        } else if (tid < 136) {
            kall[t][tid - 128] = Aug[0][tid - 128][24];
        }
        if (tid < 16) {
            float s = c_sh[t][tid];   // q
            #pragma unroll
            for (int q = 0; q < 16; ++q) s = fmaf(At_sh[tid][q], p_sh[pb][q], s);
            float s2 = 0.f;
            #pragma unroll
            for (int q = 0; q < 8; ++q) s2 = fmaf(Gu[tid][q], Aug[0][q][24], s2);
            const float v = s - s2;
            p_sh[pb ^ 1][tid] = v;
            pws[t * 16 + tid] = v;
        }
        if (t > 0) { // commit prefetched C_{t-1}
            Csh[cb ^ 1][tid / 24][tid % 24] = pf0;
            Csh[cb ^ 1][(tid + 256) / 24][(tid + 256) % 24] = pf1;
            if (tid < 64) Csh[cb ^ 1][(tid + 512) / 24][(tid + 512) % 24] = pf2;
        }
        __syncthreads();
        pb ^= 1;
    }

    // ---- forward rollout + mu ----
    if (tid < 16) z_sh[0][tid] = gx0[tid];
    __syncthreads();
    for (int t = 0; t < T; ++t) {
        if (tid < 8) {                       // u_t = -(K_t x_t + k_t)
            float s = kall[t][tid];
            #pragma unroll
            for (int q = 0; q < 16; ++q) s = fmaf(Kall[t][tid][q], z_sh[t][q], s);
            z_sh[t][16 + tid] = -s;
        }
        if (tid >= 32 && tid < 48) {         // mu_t = +/- (P_t x_t + p_t)
            const int i = tid - 32;
            float s = pws[t * 16 + i];
            const float* Prow = Pws + t * 256 + i * 16;
            #pragma unroll
            for (int q = 0; q < 16; ++q) s = fmaf(Prow[q], z_sh[t][q], s);
            if (t == 0) s = -s;              // mu_0 = -(P_0 x_0 + p_0)
            out[T * NA + t * 16 + i] = s;
        }
        __syncthreads();
        if (t < T - 1 && tid < 16) {         // x_{t+1} = A x_t + B u_t
            float s = 0.f;
            #pragma unroll
            for (int q = 0; q < 16; ++q) s = fmaf(A_sh[tid][q], z_sh[t][q], s);
            #pragma unroll
            for (int q = 0; q < 8; ++q) s = fmaf(B_sh[tid][q], z_sh[t][16 + q], s);
            z_sh[t + 1][tid] = s;
        }
        __syncthreads();
    }

    // ---- write z ----
    for (int idx = tid; idx < T * NA; idx += 256)
        out[idx] = z_sh[idx / 24][idx % 24];
}

extern "C" void kernel_launch(void* const* d_in, const int* in_sizes, int n_in,
                              void* d_out, int out_size, void* d_ws, size_t ws_size,
                              hipStream_t stream) {
    const float* gA  = (const float*)d_in[0];
    const float* gB  = (const float*)d_in[1];
    const float* gx0 = (const float*)d_in[2];
    const float* gC  = (const float*)d_in[3];
    const float* gc  = (const float*)d_in[4];
    float* out = (float*)d_out;
    float* Pws = (float*)d_ws;           // T*256 floats
    float* pws = Pws + T * 256;          // T*16 floats  (total ~139 KB << ws)
    lqr_solve<<<dim3(1), dim3(256), 0, stream>>>(gA, gB, gx0, gC, gc, out, Pws, pws);
}

// Round 6
// 431.617 us; speedup vs baseline: 1.2290x; 1.2290x over previous
//
#include <hip/hip_runtime.h>

// LQR KKT solve via backward Riccati recursion + forward rollout.
// T=128, n_state=16, n_ctrl=8, n_all=24. Single block, 256 threads.
// Base: the PROVEN round-2 kernel (487us, absmax 0.0039).
// SINGLE delta this round (A/B isolation after R5's 2-delta NaN):
//   Gauss-Jordan: 8 scalar rounds -> 4 rounds of 2x2 block pivots
//   (H SPD >= I, Schur complements stay >= I -> dets >= 1, pivot-free safe).
// Gu is computed EXACTLY as in R2 (separate tid<128 matmul) -- the dual-write
// delta from R5 is NOT included.
// mu_t computed as P_t x_t + p_t (stable), NOT via the costate recursion
// (A has spectral radius ~1.2 -> costate recursion amplifies error 1.2^128).

constexpr int T  = 128;
constexpr int NA = 24;

__global__ __launch_bounds__(256, 1)
void lqr_solve(const float* __restrict__ gA,
               const float* __restrict__ gB,
               const float* __restrict__ gx0,
               const float* __restrict__ gC,
               const float* __restrict__ gc,
               float* __restrict__ out,
               float* __restrict__ Pws,   // [T*256] scratch: P_t row-major
               float* __restrict__ pws)   // [T*16]  scratch: p_t
{
    __shared__ float A_sh[16][16];   // A row-major
    __shared__ float At_sh[16][16];  // A^T row-major (contiguous columns of A)
    __shared__ float B_sh[16][8];
    __shared__ float Bt_sh[8][16];
    __shared__ float P_sh[2][16][16]; // double-buffered P_{t+1} / P_t
    __shared__ float p_sh[2][16];
    __shared__ float Wt[16][16];     // Wt[j][k] = (P' A)[k][j]  (transposed)
    __shared__ float Vt[8][16];      // Vt[j][k] = (P' B)[k][j]
    __shared__ float Gu[16][8];      // S + A^T P' B
    __shared__ float Aug[2][8][27];  // ping-pong [H | G | rhs], 25 used cols
    __shared__ float Kall[T][8][16];
    __shared__ float kall[T][8];
    __shared__ float c_sh[T][NA];
    __shared__ float z_sh[T][NA];    // x_t = [0:16), u_t = [16:24)
    __shared__ float Csh[2][24][25]; // double-buffered C_t (padded rows)

    const int tid = threadIdx.x;

    // ---- init: load A, B, c, C_{T-1}; P_T = 0, p_T = 0 ----
    {
        const int i = tid >> 4, j = tid & 15;
        const float v = gA[tid];
        A_sh[i][j] = v; At_sh[j][i] = v;
        P_sh[0][i][j] = 0.0f;
    }
    if (tid < 128) {
        const int i = tid >> 3, j = tid & 7;
        const float v = gB[tid];
        B_sh[i][j] = v; Bt_sh[j][i] = v;
    }
    if (tid < 16) p_sh[0][tid] = 0.0f;
    for (int idx = tid; idx < T * NA; idx += 256) c_sh[idx / NA][idx % NA] = gc[idx];
    for (int idx = tid; idx < 576; idx += 256)
        Csh[0][idx / 24][idx % 24] = gC[(T - 1) * 576 + idx];
    __syncthreads();

    // ---- backward Riccati pass ----
    int pb = 0; // P_sh buffer holding P_{t+1}
    for (int t = T - 1; t >= 0; --t) {
        const int cb = (T - 1 - t) & 1; // Csh buffer holding C_t

        // register-prefetch C_{t-1} (written to LDS in phase 5)
        float pf0 = 0.f, pf1 = 0.f, pf2 = 0.f;
        if (t > 0) {
            const float* src = gC + (size_t)(t - 1) * 576;
            pf0 = src[tid];
            pf1 = src[tid + 256];
            if (tid < 64) pf2 = src[tid + 512];
        }

        // phase 1+2: Wt = (P'A)^T, Vt = (P'B)^T  (contiguous row reads)
        {
            const int j = tid >> 4, k = tid & 15;
            float s = 0.f;
            #pragma unroll
            for (int q = 0; q < 16; ++q) s = fmaf(P_sh[pb][k][q], At_sh[j][q], s);
            Wt[j][k] = s;
            if (tid < 128) {
                float s2 = 0.f;
                #pragma unroll
                for (int q = 0; q < 16; ++q) s2 = fmaf(P_sh[pb][k][q], Bt_sh[j][q], s2);
                Vt[j][k] = s2;
            }
        }
        __syncthreads();

        // phase 3: Aug = [H | G | rhs] (8x25) and Gu = S + A^T V (16x8)
        if (tid < 200) {
            const int i = tid / 25, j = tid % 25;
            float s;
            if (j < 8) {                    // H = R + B^T P' B
                s = Csh[cb][16 + i][16 + j];
                #pragma unroll
                for (int q = 0; q < 16; ++q) s = fmaf(Bt_sh[i][q], Vt[j][q], s);
            } else if (j < 24) {            // G = S^t + B^T P' A
                const int jj = j - 8;
                s = Csh[cb][16 + i][jj];
                #pragma unroll
                for (int q = 0; q < 16; ++q) s = fmaf(Bt_sh[i][q], Wt[jj][q], s);
            } else {                        // rhs = r + B^T p'
                s = c_sh[t][16 + i];
                #pragma unroll
                for (int q = 0; q < 16; ++q) s = fmaf(Bt_sh[i][q], p_sh[pb][q], s);
            }
            Aug[0][i][j] = s;
        }
        if (tid < 128) {
            const int i = tid >> 3, j = tid & 7;
            float s = Csh[cb][i][16 + j];
            #pragma unroll
            for (int q = 0; q < 16; ++q) s = fmaf(At_sh[i][q], Vt[j][q], s);
            Gu[i][j] = s;
        }
        __syncthreads();

        // phase 4: Gauss-Jordan, 2x2 block pivots (4 rounds, 1 barrier each).
        // Rounds kk=0,2,4,6 read rb=0,1,0,1 / write wb -> result in Aug[0].
        #pragma unroll
        for (int kk = 0; kk < 8; kk += 2) {
            const int rb = (kk >> 1) & 1, wb = rb ^ 1;
            if (tid < 200) {
                const int i = tid / 25, j = tid % 25;
                const float a  = Aug[rb][kk][kk],     b = Aug[rb][kk][kk + 1];
                const float c2 = Aug[rb][kk + 1][kk], d = Aug[rb][kk + 1][kk + 1];
                const float rdet = 1.0f / fmaf(a, d, -b * c2);
                const float pk0 = Aug[rb][kk][j], pk1 = Aug[rb][kk + 1][j];
                const float w0 = (d * pk0 - b * pk1) * rdet;
                const float w1 = (a * pk1 - c2 * pk0) * rdet;
                float v;
                if (i == kk)          v = w0;
                else if (i == kk + 1) v = w1;
                else v = fmaf(-Aug[rb][i][kk], w0,
                              fmaf(-Aug[rb][i][kk + 1], w1, Aug[rb][i][j]));
                Aug[wb][i][j] = v;
            }
            __syncthreads();
        }
        // Aug[0] = [I | K | k],  K = H^-1 G,  k = H^-1 rhs

        // phase 5: P_t = Q + A^T W - Gu K ; p_t = q + A^T p' - Gu k ; save K,k
        {
            const int i = tid >> 4, j = tid & 15;
            float s = Csh[cb][i][j];  // Q
            #pragma unroll
            for (int q = 0; q < 16; ++q) s = fmaf(At_sh[i][q], Wt[j][q], s);
            float s2 = 0.f;
            #pragma unroll
            for (int q = 0; q < 8; ++q) s2 = fmaf(Gu[i][q], Aug[0][q][8 + j], s2);
            const float v = s - s2;
            P_sh[pb ^ 1][i][j] = v;
            Pws[t * 256 + tid] = v;   // for mu_t = P_t x_t + p_t later
        }
        if (tid < 128) {
            const int i = tid >> 4, j = tid & 15;
            Kall[t][i][j] = Aug[0][i][8 + j];
        } else if (tid < 136) {
            kall[t][tid - 128] = Aug[0][tid - 128][24];
        }
        if (tid < 16) {
            float s = c_sh[t][tid];   // q
            #pragma unroll
            for (int q = 0; q < 16; ++q) s = fmaf(At_sh[tid][q], p_sh[pb][q], s);
            float s2 = 0.f;
            #pragma unroll
            for (int q = 0; q < 8; ++q) s2 = fmaf(Gu[tid][q], Aug[0][q][24], s2);
            const float v = s - s2;
            p_sh[pb ^ 1][tid] = v;
            pws[t * 16 + tid] = v;
        }
        if (t > 0) { // commit prefetched C_{t-1}
            Csh[cb ^ 1][tid / 24][tid % 24] = pf0;
            Csh[cb ^ 1][(tid + 256) / 24][(tid + 256) % 24] = pf1;
            if (tid < 64) Csh[cb ^ 1][(tid + 512) / 24][(tid + 512) % 24] = pf2;
        }
        __syncthreads();
        pb ^= 1;
    }

    // ---- forward rollout + mu ----
    if (tid < 16) z_sh[0][tid] = gx0[tid];
    __syncthreads();
    for (int t = 0; t < T; ++t) {
        if (tid < 8) {                       // u_t = -(K_t x_t + k_t)
            float s = kall[t][tid];
            #pragma unroll
            for (int q = 0; q < 16; ++q) s = fmaf(Kall[t][tid][q], z_sh[t][q], s);
            z_sh[t][16 + tid] = -s;
        }
        if (tid >= 32 && tid < 48) {         // mu_t = +/- (P_t x_t + p_t)
            const int i = tid - 32;
            float s = pws[t * 16 + i];
            const float* Prow = Pws + t * 256 + i * 16;
            #pragma unroll
            for (int q = 0; q < 16; ++q) s = fmaf(Prow[q], z_sh[t][q], s);
            if (t == 0) s = -s;              // mu_0 = -(P_0 x_0 + p_0)
            out[T * NA + t * 16 + i] = s;
        }
        __syncthreads();
        if (t < T - 1 && tid < 16) {         // x_{t+1} = A x_t + B u_t
            float s = 0.f;
            #pragma unroll
            for (int q = 0; q < 16; ++q) s = fmaf(A_sh[tid][q], z_sh[t][q], s);
            #pragma unroll
            for (int q = 0; q < 8; ++q) s = fmaf(B_sh[tid][q], z_sh[t][16 + q], s);
            z_sh[t + 1][tid] = s;
        }
        __syncthreads();
    }

    // ---- write z ----
    for (int idx = tid; idx < T * NA; idx += 256)
        out[idx] = z_sh[idx / 24][idx % 24];
}

extern "C" void kernel_launch(void* const* d_in, const int* in_sizes, int n_in,
                              void* d_out, int out_size, void* d_ws, size_t ws_size,
                              hipStream_t stream) {
    const float* gA  = (const float*)d_in[0];
    const float* gB  = (const float*)d_in[1];
    const float* gx0 = (const float*)d_in[2];
    const float* gC  = (const float*)d_in[3];
    const float* gc  = (const float*)d_in[4];
    float* out = (float*)d_out;
    float* Pws = (float*)d_ws;           // T*256 floats
    float* pws = Pws + T * 256;          // T*16 floats  (total ~139 KB << ws)
    lqr_solve<<<dim3(1), dim3(256), 0, stream>>>(gA, gB, gx0, gC, gc, out, Pws, pws);
}

// Round 7
// 408.159 us; speedup vs baseline: 1.2996x; 1.0575x over previous
//
#include <hip/hip_runtime.h>

// LQR KKT solve via backward Riccati recursion + forward rollout.
// T=128, n_state=16, n_ctrl=8, n_all=24. Single block, 256 threads.
// Base: the PROVEN round-6 kernel (378us, absmax 0.0039; 2x2-block GJ).
// SINGLE delta this round: float4-vectorized LDS dot products with
// conflict-avoiding padding (P_sh/Wt/Vt row stride 16 -> 20 floats).
// Thread mapping, phases, barriers, scalar GJ: identical to R6.
// NOTE: the Gu dual-write (R3/R4/R5) is empirically convicted of NaN --
// Gu keeps its own matmul. mu_t = P_t x_t + p_t (stable) as before.

constexpr int T  = 128;
constexpr int NA = 24;

// 16-element dot product via 4x float4 LDS reads. Both ptrs 16B-aligned.
__device__ __forceinline__ float dot16f4(const float* a, const float* b, float s) {
    const float4* a4 = (const float4*)a;
    const float4* b4 = (const float4*)b;
#pragma unroll
    for (int q = 0; q < 4; ++q) {
        float4 x = a4[q], y = b4[q];
        s = fmaf(x.x, y.x, s); s = fmaf(x.y, y.y, s);
        s = fmaf(x.z, y.z, s); s = fmaf(x.w, y.w, s);
    }
    return s;
}

__global__ __launch_bounds__(256, 1)
void lqr_solve(const float* __restrict__ gA,
               const float* __restrict__ gB,
               const float* __restrict__ gx0,
               const float* __restrict__ gC,
               const float* __restrict__ gc,
               float* __restrict__ out,
               float* __restrict__ Pws,   // [T*256] scratch: P_t row-major
               float* __restrict__ pws)   // [T*16]  scratch: p_t
{
    __shared__ __align__(16) float A_sh[16][16];   // A row-major
    __shared__ __align__(16) float At_sh[16][16];  // A^T row-major
    __shared__ __align__(16) float B_sh[16][8];
    __shared__ __align__(16) float Bt_sh[8][16];
    __shared__ __align__(16) float P_sh[2][16][20]; // padded stride 20
    __shared__ __align__(16) float p_sh[2][16];
    __shared__ __align__(16) float Wt[16][20];     // Wt[j][k] = (P'A)[k][j]
    __shared__ __align__(16) float Vt[8][20];      // Vt[j][k] = (P'B)[k][j]
    __shared__ __align__(16) float Gu[16][8];      // S + A^T P' B
    __shared__ __align__(16) float Aug[2][8][27];  // ping-pong [H|G|rhs]
    __shared__ __align__(16) float Kall[T][8][16];
    __shared__ __align__(16) float kall[T][8];
    __shared__ __align__(16) float c_sh[T][NA];
    __shared__ __align__(16) float z_sh[T][NA];    // x=[0:16), u=[16:24)
    __shared__ __align__(16) float Csh[2][24][25]; // double-buffered C_t

    const int tid = threadIdx.x;

    // ---- init: load A, B, c, C_{T-1}; P_T = 0, p_T = 0 ----
    {
        const int i = tid >> 4, j = tid & 15;
        const float v = gA[tid];
        A_sh[i][j] = v; At_sh[j][i] = v;
        P_sh[0][i][j] = 0.0f;
        if (j < 4) P_sh[0][i][16 + j] = 0.0f;  // zero the pad too
    }
    if (tid < 128) {
        const int i = tid >> 3, j = tid & 7;
        const float v = gB[tid];
        B_sh[i][j] = v; Bt_sh[j][i] = v;
    }
    if (tid < 16) p_sh[0][tid] = 0.0f;
    for (int idx = tid; idx < T * NA; idx += 256) c_sh[idx / NA][idx % NA] = gc[idx];
    for (int idx = tid; idx < 576; idx += 256)
        Csh[0][idx / 24][idx % 24] = gC[(T - 1) * 576 + idx];
    __syncthreads();

    // ---- backward Riccati pass ----
    int pb = 0; // P_sh buffer holding P_{t+1}
    for (int t = T - 1; t >= 0; --t) {
        const int cb = (T - 1 - t) & 1; // Csh buffer holding C_t

        // register-prefetch C_{t-1} (written to LDS in phase 5)
        float pf0 = 0.f, pf1 = 0.f, pf2 = 0.f;
        if (t > 0) {
            const float* src = gC + (size_t)(t - 1) * 576;
            pf0 = src[tid];
            pf1 = src[tid + 256];
            if (tid < 64) pf2 = src[tid + 512];
        }

        // phase 1+2: Wt = (P'A)^T, Vt = (P'B)^T  (float4 row reads)
        {
            const int j = tid >> 4, k = tid & 15;
            Wt[j][k] = dot16f4(&P_sh[pb][k][0], &At_sh[j][0], 0.0f);
            if (tid < 128) {
                const int jb = tid >> 4;  // 0..7
                Vt[jb][k] = dot16f4(&P_sh[pb][k][0], &Bt_sh[jb][0], 0.0f);
            }
        }
        __syncthreads();

        // phase 3: Aug = [H | G | rhs] (8x25) and Gu = S + A^T V (16x8)
        if (tid < 200) {
            const int i = tid / 25, j = tid % 25;
            float s;
            if (j < 8) {                    // H = R + B^T P' B
                s = dot16f4(&Bt_sh[i][0], &Vt[j][0], Csh[cb][16 + i][16 + j]);
            } else if (j < 24) {            // G = S^t + B^T P' A
                const int jj = j - 8;
                s = dot16f4(&Bt_sh[i][0], &Wt[jj][0], Csh[cb][16 + i][jj]);
            } else {                        // rhs = r + B^T p'
                s = dot16f4(&Bt_sh[i][0], &p_sh[pb][0], c_sh[t][16 + i]);
            }
            Aug[0][i][j] = s;
        }
        if (tid < 128) {
            const int i = tid >> 3, j = tid & 7;
            Gu[i][j] = dot16f4(&At_sh[i][0], &Vt[j][0], Csh[cb][i][16 + j]);
        }
        __syncthreads();

        // phase 4: Gauss-Jordan, 2x2 block pivots (4 rounds, 1 barrier each).
        // Rounds kk=0,2,4,6 read rb=0,1,0,1 / write wb -> result in Aug[0].
        #pragma unroll
        for (int kk = 0; kk < 8; kk += 2) {
            const int rb = (kk >> 1) & 1, wb = rb ^ 1;
            if (tid < 200) {
                const int i = tid / 25, j = tid % 25;
                const float a  = Aug[rb][kk][kk],     b = Aug[rb][kk][kk + 1];
                const float c2 = Aug[rb][kk + 1][kk], d = Aug[rb][kk + 1][kk + 1];
                const float rdet = 1.0f / fmaf(a, d, -b * c2);
                const float pk0 = Aug[rb][kk][j], pk1 = Aug[rb][kk + 1][j];
                const float w0 = (d * pk0 - b * pk1) * rdet;
                const float w1 = (a * pk1 - c2 * pk0) * rdet;
                float v;
                if (i == kk)          v = w0;
                else if (i == kk + 1) v = w1;
                else v = fmaf(-Aug[rb][i][kk], w0,
                              fmaf(-Aug[rb][i][kk + 1], w1, Aug[rb][i][j]));
                Aug[wb][i][j] = v;
            }
            __syncthreads();
        }
        // Aug[0] = [I | K | k],  K = H^-1 G,  k = H^-1 rhs

        // phase 5: P_t = Q + A^T W - Gu K ; p_t = q + A^T p' - Gu k ; save K,k
        {
            const int i = tid >> 4, j = tid & 15;
            float s = dot16f4(&At_sh[i][0], &Wt[j][0], Csh[cb][i][j]);
            // kc = K column j (8 scalar reads, lanes read consecutive floats)
            float s2 = 0.f;
            const float4 g0 = *(const float4*)&Gu[i][0];
            const float4 g1 = *(const float4*)&Gu[i][4];
            s2 = fmaf(g0.x, Aug[0][0][8 + j], s2);
            s2 = fmaf(g0.y, Aug[0][1][8 + j], s2);
            s2 = fmaf(g0.z, Aug[0][2][8 + j], s2);
            s2 = fmaf(g0.w, Aug[0][3][8 + j], s2);
            s2 = fmaf(g1.x, Aug[0][4][8 + j], s2);
            s2 = fmaf(g1.y, Aug[0][5][8 + j], s2);
            s2 = fmaf(g1.z, Aug[0][6][8 + j], s2);
            s2 = fmaf(g1.w, Aug[0][7][8 + j], s2);
            const float v = s - s2;
            P_sh[pb ^ 1][i][j] = v;
            Pws[t * 256 + tid] = v;   // for mu_t = P_t x_t + p_t later
        }
        if (tid < 128) {
            const int i = tid >> 4, j = tid & 15;
            Kall[t][i][j] = Aug[0][i][8 + j];
        } else if (tid < 136) {
            kall[t][tid - 128] = Aug[0][tid - 128][24];
        }
        if (tid < 16) {
            float s = dot16f4(&At_sh[tid][0], &p_sh[pb][0], c_sh[t][tid]);
            float s2 = 0.f;
            #pragma unroll
            for (int q = 0; q < 8; ++q) s2 = fmaf(Gu[tid][q], Aug[0][q][24], s2);
            const float v = s - s2;
            p_sh[pb ^ 1][tid] = v;
            pws[t * 16 + tid] = v;
        }
        if (t > 0) { // commit prefetched C_{t-1}
            Csh[cb ^ 1][tid / 24][tid % 24] = pf0;
            Csh[cb ^ 1][(tid + 256) / 24][(tid + 256) % 24] = pf1;
            if (tid < 64) Csh[cb ^ 1][(tid + 512) / 24][(tid + 512) % 24] = pf2;
        }
        __syncthreads();
        pb ^= 1;
    }

    // ---- forward rollout + mu ----
    if (tid < 16) z_sh[0][tid] = gx0[tid];
    __syncthreads();
    for (int t = 0; t < T; ++t) {
        if (tid < 8) {                       // u_t = -(K_t x_t + k_t)
            float s = dot16f4(&Kall[t][tid][0], &z_sh[t][0], kall[t][tid]);
            z_sh[t][16 + tid] = -s;
        }
        if (tid >= 32 && tid < 48) {         // mu_t = +/- (P_t x_t + p_t)
            const int i = tid - 32;
            float s = pws[t * 16 + i];
            const float4* Pr = (const float4*)(Pws + t * 256 + i * 16);
            const float4* zr = (const float4*)&z_sh[t][0];
            #pragma unroll
            for (int q = 0; q < 4; ++q) {
                float4 p = Pr[q], z = zr[q];
                s = fmaf(p.x, z.x, s); s = fmaf(p.y, z.y, s);
                s = fmaf(p.z, z.z, s); s = fmaf(p.w, z.w, s);
            }
            if (t == 0) s = -s;              // mu_0 = -(P_0 x_0 + p_0)
            out[T * NA + t * 16 + i] = s;
        }
        __syncthreads();
        if (t < T - 1 && tid < 16) {         // x_{t+1} = A x_t + B u_t
            float s = dot16f4(&A_sh[tid][0], &z_sh[t][0], 0.0f);
            const float4 b0 = *(const float4*)&B_sh[tid][0];
            const float4 b1 = *(const float4*)&B_sh[tid][4];
            const float4 u0 = *(const float4*)&z_sh[t][16];
            const float4 u1 = *(const float4*)&z_sh[t][20];
            s = fmaf(b0.x, u0.x, s); s = fmaf(b0.y, u0.y, s);
            s = fmaf(b0.z, u0.z, s); s = fmaf(b0.w, u0.w, s);
            s = fmaf(b1.x, u1.x, s); s = fmaf(b1.y, u1.y, s);
            s = fmaf(b1.z, u1.z, s); s = fmaf(b1.w, u1.w, s);
            z_sh[t + 1][tid] = s;
        }
        __syncthreads();
    }

    // ---- write z ----
    for (int idx = tid; idx < T * NA; idx += 256)
        out[idx] = z_sh[idx / 24][idx % 24];
}

extern "C" void kernel_launch(void* const* d_in, const int* in_sizes, int n_in,
                              void* d_out, int out_size, void* d_ws, size_t ws_size,
                              hipStream_t stream) {
    const float* gA  = (const float*)d_in[0];
    const float* gB  = (const float*)d_in[1];
    const float* gx0 = (const float*)d_in[2];
    const float* gC  = (const float*)d_in[3];
    const float* gc  = (const float*)d_in[4];
    float* out = (float*)d_out;
    float* Pws = (float*)d_ws;           // T*256 floats
    float* pws = Pws + T * 256;          // T*16 floats  (total ~139 KB << ws)
    lqr_solve<<<dim3(1), dim3(256), 0, stream>>>(gA, gB, gx0, gC, gc, out, Pws, pws);
}